// Round 3
// baseline (212.401 us; speedup 1.0000x reference)
//
#include <hip/hip_runtime.h>
#include <stdint.h>

typedef unsigned short u16;
typedef __attribute__((ext_vector_type(8))) short short8;
typedef __attribute__((ext_vector_type(4))) float f32x4;
typedef __attribute__((ext_vector_type(2))) unsigned uint2v;

#define AS1C(p) ((const __attribute__((address_space(1))) void*)(p))
#define AS3(p)  ((__attribute__((address_space(3))) void*)(p))

__device__ __forceinline__ u16 to_bf16(float f) {
  unsigned u = __builtin_bit_cast(unsigned, f);
  u += 0x7FFFu + ((u >> 16) & 1u);
  return (u16)(u >> 16);
}

// ---------------------------------------------------------------------------
// x[b][c][n] fp32 -> xT[b][n][c] bf16   (B=16, C=512, N=1024)
__global__ __launch_bounds__(256) void xpose_cvt(const float* __restrict__ x,
                                                 u16* __restrict__ xT) {
  __shared__ float t[32][33];
  int b = blockIdx.z;
  int n0 = blockIdx.x * 32, c0 = blockIdx.y * 32;
  int tx = threadIdx.x & 31, ty = threadIdx.x >> 5;  // ty 0..7
  const float* xp = x + (size_t)b * 512 * 1024;
#pragma unroll
  for (int i = 0; i < 32; i += 8)
    t[ty + i][tx] = xp[(size_t)(c0 + ty + i) * 1024 + n0 + tx];
  __syncthreads();
  u16* op = xT + (size_t)b * 1024 * 512;
#pragma unroll
  for (int i = 0; i < 32; i += 8)
    op[(size_t)(n0 + ty + i) * 512 + c0 + tx] = to_bf16(t[tx][ty + i]);
}

__global__ __launch_bounds__(256) void cvt_bf16(const float* __restrict__ s,
                                                u16* __restrict__ d, int n) {
  int i = blockIdx.x * 256 + threadIdx.x;
  if (i < n) d[i] = to_bf16(s[i]);
}

// ---------------------------------------------------------------------------
// Generic 128x128-tile bf16 GEMM, K=512, BK=32 (m97 structure, unchanged).
template <int MODE>
__global__ __launch_bounds__(256) void gemm_bt(
    const u16* __restrict__ Abase, const u16* __restrict__ Bbase,
    long saB, long sbB,
    const float* __restrict__ bias, const float* __restrict__ xres,
    const float* __restrict__ gammap,
    u16* __restrict__ oq, u16* __restrict__ ok, u16* __restrict__ ov,
    float* __restrict__ of) {
  __shared__ __align__(16) u16 lsA[128 * 32];
  __shared__ __align__(16) u16 lsB[128 * 32];
  int b = blockIdx.z;
  const u16* Ag = Abase + (size_t)b * saB;
  const u16* Bg = Bbase + (size_t)b * sbB;
  int m0 = blockIdx.y * 128, n0 = blockIdx.x * 128;
  int tid = threadIdx.x;
  int w = tid >> 6, l = tid & 63;
  int wr = w >> 1, wc = w & 1;
  int lq = l >> 4, lr = l & 15;
  int rowA = w * 32 + (l >> 2);
  int k8 = (l & 3) * 8;
  f32x4 acc[4][4] = {};
  for (int kk = 0; kk < 16; ++kk) {
    int ko = kk * 32;
    __builtin_amdgcn_global_load_lds(
        AS1C(Ag + (size_t)(m0 + rowA) * 512 + ko + k8),
        AS3(&lsA[rowA * 32 + k8]), 16, 0, 0);
    __builtin_amdgcn_global_load_lds(
        AS1C(Ag + (size_t)(m0 + rowA + 16) * 512 + ko + k8),
        AS3(&lsA[(rowA + 16) * 32 + k8]), 16, 0, 0);
    __builtin_amdgcn_global_load_lds(
        AS1C(Bg + (size_t)(n0 + rowA) * 512 + ko + k8),
        AS3(&lsB[rowA * 32 + k8]), 16, 0, 0);
    __builtin_amdgcn_global_load_lds(
        AS1C(Bg + (size_t)(n0 + rowA + 16) * 512 + ko + k8),
        AS3(&lsB[(rowA + 16) * 32 + k8]), 16, 0, 0);
    __syncthreads();
    short8 af[4], bfr[4];
#pragma unroll
    for (int m = 0; m < 4; ++m)
      af[m] = *(const short8*)&lsA[(wr * 64 + m * 16 + lr) * 32 + lq * 8];
#pragma unroll
    for (int j = 0; j < 4; ++j)
      bfr[j] = *(const short8*)&lsB[(wc * 64 + j * 16 + lr) * 32 + lq * 8];
#pragma unroll
    for (int m = 0; m < 4; ++m)
#pragma unroll
      for (int j = 0; j < 4; ++j)
        acc[m][j] = __builtin_amdgcn_mfma_f32_16x16x32_bf16(af[m], bfr[j],
                                                            acc[m][j], 0, 0, 0);
    __syncthreads();
  }
  float g = (MODE == 2) ? gammap[0] : 0.f;
#pragma unroll
  for (int m = 0; m < 4; ++m)
#pragma unroll
    for (int j = 0; j < 4; ++j)
#pragma unroll
      for (int e = 0; e < 4; ++e) {
        int row = m0 + wr * 64 + m * 16 + lq * 4 + e;
        int col = n0 + wc * 64 + j * 16 + lr;
        float v = acc[m][j][e];
        if (MODE == 0) {
          int o = col, n = row;
          v += bias[o];
          int oo = (o < 512) ? o : o - 512;
          int hh = oo >> 6, cc = oo & 63;
          u16* dst = (o < 512) ? oq : ok;
          dst[((size_t)(b * 8 + hh) * 1024 + n) * 64 + cc] = to_bf16(v);
        } else if (MODE == 1) {
          int o = row, n = col;
          v += bias[o];  // bias pre-offset by +1024 on host side
          int hh = o >> 6, cc = o & 63;
          ov[((size_t)(b * 8 + hh) * 64 + cc) * 1024 + n] = to_bf16(v);
        } else {
          int o = row, n = col;
          v += bias[o];
          size_t idx = ((size_t)b * 512 + o) * 1024 + n;
          of[idx] = g * v + xres[idx];
        }
      }
}

// ---------------------------------------------------------------------------
// Flash attention, barrier-free + software-pipelined. Q/K [bh][n][64] bf16,
// V [bh][c][n] bf16. 4 waves x 32 q-rows; KBLK=64. Swapped QK^T (S=mfma(K,Q)).
// Constant-max softmax: P = exp2(S*CS - 16*CS) -- no online max, no rescale,
// no cross-lane ops in the k-loop. Row-sum via ones-MFMA (lands in O layout).
// Pipeline: exp(t) | QKT(t+1) | PV(t), so exp never stalls on fresh MFMAs.
#define CS 0.18033688f   // (1/sqrt(64)) * log2(e)
#define MCC 2.8853901f   // 16 * CS

__global__ __launch_bounds__(256, 4) void attn_fused(const u16* __restrict__ Qb,
                                                     const u16* __restrict__ Kb,
                                                     const u16* __restrict__ Vb,
                                                     u16* __restrict__ attnT) {
  __shared__ __align__(16) u16 Plds[4][2048];  // 4KB per wave, XOR-swizzled
  int L = blockIdx.x;
  // XCD-bijective swizzle: all 8 n-blocks of a bh land on one XCD (L2 reuse)
  int bh = (L & 7) | ((L >> 6) << 3);
  int nb = (L >> 3) & 7;
  int b = bh >> 3, h = bh & 7;
  int tid = threadIdx.x, w = tid >> 6, lane = tid & 63;
  int g = lane >> 4, lr = lane & 15;
  char* Pb = (char*)(&Plds[w][0]);
  const u16* Qh = Qb + (size_t)bh * 65536;
  const u16* Kh = Kb + (size_t)bh * 65536;
  const u16* Vh = Vb + (size_t)bh * 65536;
  int n_base = nb * 128 + w * 32;
  int sz = (lr & 7) << 4;  // XOR swizzle for this lane's P rows

  const short8 onesf = {0x3F80, 0x3F80, 0x3F80, 0x3F80,
                        0x3F80, 0x3F80, 0x3F80, 0x3F80};  // bf16 1.0 x8

  short8 qf[2][2];
#pragma unroll
  for (int r = 0; r < 2; ++r)
#pragma unroll
    for (int ks = 0; ks < 2; ++ks)
      qf[r][ks] = *(const short8*)&Qh[(size_t)(n_base + r * 16 + lr) * 64 +
                                      ks * 32 + g * 8];

  f32x4 O[2][4] = {};
  f32x4 lacc[2] = {};

  // ---- prologue: K(0), S(0), K(1), V(0)
  short8 kf[4][2];
#pragma unroll
  for (int j = 0; j < 4; ++j)
#pragma unroll
    for (int ks = 0; ks < 2; ++ks)
      kf[j][ks] =
          *(const short8*)&Kh[(size_t)(j * 16 + lr) * 64 + ks * 32 + g * 8];
  f32x4 S[4][2];
#pragma unroll
  for (int j = 0; j < 4; ++j)
#pragma unroll
    for (int r = 0; r < 2; ++r) {
      f32x4 z = {};
      z = __builtin_amdgcn_mfma_f32_16x16x32_bf16(kf[j][0], qf[r][0], z, 0, 0, 0);
      z = __builtin_amdgcn_mfma_f32_16x16x32_bf16(kf[j][1], qf[r][1], z, 0, 0, 0);
      S[j][r] = z;
    }
#pragma unroll
  for (int j = 0; j < 4; ++j)
#pragma unroll
    for (int ks = 0; ks < 2; ++ks)
      kf[j][ks] = *(const short8*)&Kh[(size_t)(64 + j * 16 + lr) * 64 +
                                      ks * 32 + g * 8];
  short8 vf[4][2];
#pragma unroll
  for (int jc = 0; jc < 4; ++jc)
#pragma unroll
    for (int ks = 0; ks < 2; ++ks)
      vf[jc][ks] =
          *(const short8*)&Vh[(size_t)(jc * 16 + lr) * 1024 + ks * 32 + g * 8];

  for (int kb = 0; kb < 16; ++kb) {
    // ---- a) exp/pack S(kb) -> P LDS (S drained: PV(kb-1) issued after it)
#pragma unroll
    for (int r = 0; r < 2; ++r) {
      int rowoff = (r * 16 + lr) * 128;
#pragma unroll
      for (int j = 0; j < 4; ++j) {
        float p0 = __builtin_amdgcn_exp2f(__builtin_fmaf(S[j][r][0], CS, -MCC));
        float p1 = __builtin_amdgcn_exp2f(__builtin_fmaf(S[j][r][1], CS, -MCC));
        float p2 = __builtin_amdgcn_exp2f(__builtin_fmaf(S[j][r][2], CS, -MCC));
        float p3 = __builtin_amdgcn_exp2f(__builtin_fmaf(S[j][r][3], CS, -MCC));
        unsigned w0, w1;
        asm("v_cvt_pk_bf16_f32 %0, %1, %2" : "=v"(w0) : "v"(p0), "v"(p1));
        asm("v_cvt_pk_bf16_f32 %0, %1, %2" : "=v"(w1) : "v"(p2), "v"(p3));
        *(uint2v*)(Pb + rowoff + ((j * 32 + g * 8) ^ sz)) = (uint2v){w0, w1};
      }
    }
    // ---- c) S = QKT(kb+1)  (kf = K(kb+1); hides under reads + PV issue)
#pragma unroll
    for (int j = 0; j < 4; ++j)
#pragma unroll
      for (int r = 0; r < 2; ++r) {
        f32x4 z = {};
        z = __builtin_amdgcn_mfma_f32_16x16x32_bf16(kf[j][0], qf[r][0], z, 0, 0, 0);
        z = __builtin_amdgcn_mfma_f32_16x16x32_bf16(kf[j][1], qf[r][1], z, 0, 0, 0);
        S[j][r] = z;
      }
    // ---- d) kf <- K(kb+2)  (wrap; tail loads are harmless)
    {
      int mm2 = ((kb + 2) & 15) * 64;
#pragma unroll
      for (int j = 0; j < 4; ++j)
#pragma unroll
        for (int ks = 0; ks < 2; ++ks)
          kf[j][ks] = *(const short8*)&Kh[(size_t)(mm2 + j * 16 + lr) * 64 +
                                          ks * 32 + g * 8];
    }
    // ---- e) read P(kb) fragments
    short8 pf[2][2];
#pragma unroll
    for (int r = 0; r < 2; ++r) {
      int rowoff = (r * 16 + lr) * 128;
#pragma unroll
      for (int ks = 0; ks < 2; ++ks)
        pf[r][ks] = *(const short8*)(Pb + rowoff + ((ks * 64 + g * 16) ^ sz));
    }
    // ---- f) PV + row-sum MFMAs (vf = V(kb))
#pragma unroll
    for (int r = 0; r < 2; ++r) {
      lacc[r] = __builtin_amdgcn_mfma_f32_16x16x32_bf16(pf[r][0], onesf,
                                                        lacc[r], 0, 0, 0);
      lacc[r] = __builtin_amdgcn_mfma_f32_16x16x32_bf16(pf[r][1], onesf,
                                                        lacc[r], 0, 0, 0);
#pragma unroll
      for (int jc = 0; jc < 4; ++jc) {
        O[r][jc] = __builtin_amdgcn_mfma_f32_16x16x32_bf16(pf[r][0], vf[jc][0],
                                                           O[r][jc], 0, 0, 0);
        O[r][jc] = __builtin_amdgcn_mfma_f32_16x16x32_bf16(pf[r][1], vf[jc][1],
                                                           O[r][jc], 0, 0, 0);
      }
    }
    // ---- g) vf <- V(kb+1) (wrap)
    {
      int mm1 = ((kb + 1) & 15) * 64;
#pragma unroll
      for (int jc = 0; jc < 4; ++jc)
#pragma unroll
        for (int ks = 0; ks < 2; ++ks)
          vf[jc][ks] = *(const short8*)&Vh[(size_t)(jc * 16 + lr) * 1024 + mm1 +
                                           ks * 32 + g * 8];
    }
  }
  // ---- normalize + store attnT[b][n][h*64 + c]; lacc is in O's row layout
#pragma unroll
  for (int r = 0; r < 2; ++r)
#pragma unroll
    for (int e = 0; e < 4; ++e) {
      float rl = 1.0f / lacc[r][e];
      int n = n_base + r * 16 + g * 4 + e;
#pragma unroll
      for (int jc = 0; jc < 4; ++jc)
        attnT[((size_t)b * 1024 + n) * 512 + h * 64 + jc * 16 + lr] =
            to_bf16(O[r][jc][e] * rl);
    }
}

// ---------------------------------------------------------------------------
extern "C" void kernel_launch(void* const* d_in, const int* in_sizes, int n_in,
                              void* d_out, int out_size, void* d_ws,
                              size_t ws_size, hipStream_t stream) {
  const float* x      = (const float*)d_in[0];  // (16,512,32,32)
  const float* qkv_w  = (const float*)d_in[1];  // (1536,512)
  const float* qkv_b  = (const float*)d_in[2];  // (1536,)
  const float* out_w  = (const float*)d_in[3];  // (512,512)
  const float* out_b  = (const float*)d_in[4];  // (512,)
  const float* gamma  = (const float*)d_in[5];  // (1,)
  float* out = (float*)d_out;

  u16* xT  = (u16*)d_ws;          // [16][1024][512]
  u16* Qb  = xT + 8388608;        // [128][1024][64]
  u16* Kbf = Qb + 8388608;        // [128][1024][64]
  u16* Vbf = Kbf + 8388608;       // [128][64][1024]
  u16* aT  = Vbf + 8388608;       // [16][1024][512]
  u16* wq  = aT + 8388608;        // qkv_w bf16 (1536*512)
  u16* wo  = wq + 786432;         // out_w bf16 (512*512)

  // 1) convert / transpose inputs to bf16
  xpose_cvt<<<dim3(32, 16, 16), 256, 0, stream>>>(x, xT);
  cvt_bf16<<<3072, 256, 0, stream>>>(qkv_w, wq, 786432);
  cvt_bf16<<<1024, 256, 0, stream>>>(out_w, wo, 262144);

  // 2) QKV projection. Q,K via transposed orientation (rows=n, cols=o<1024)
  gemm_bt<0><<<dim3(8, 8, 16), 256, 0, stream>>>(
      xT, wq, (long)524288, (long)0, qkv_b, nullptr, nullptr, Qb, Kbf, nullptr,
      nullptr);
  // 3) V via normal orientation (rows=o' in [0,512), cols=n)
  gemm_bt<1><<<dim3(8, 4, 16), 256, 0, stream>>>(
      wq + 524288, xT, (long)0, (long)524288, qkv_b + 1024, nullptr, nullptr,
      nullptr, nullptr, Vbf, nullptr);

  // 4) fused flash attention -> attnT[b][n][512]  (barrier-free, pipelined)
  attn_fused<<<1024, 256, 0, stream>>>(Qb, Kbf, Vbf, aT);

  // 5) output projection + bias + gamma*out + x  -> fp32 d_out
  gemm_bt<2><<<dim3(8, 4, 16), 256, 0, stream>>>(
      wo, aT, (long)0, (long)524288, out_b, x, gamma, nullptr, nullptr, nullptr,
      out);
}

// Round 5
// 135.621 us; speedup vs baseline: 1.5661x; 1.5661x over previous
//
#include <hip/hip_runtime.h>
#include <stdint.h>

typedef unsigned short u16;
typedef __attribute__((ext_vector_type(8))) short short8;
typedef __attribute__((ext_vector_type(4))) float f32x4;
typedef __attribute__((ext_vector_type(2))) unsigned uint2v;

#define AS1C(p) ((const __attribute__((address_space(1))) void*)(p))
#define AS3(p)  ((__attribute__((address_space(3))) void*)(p))

__device__ __forceinline__ u16 to_bf16(float f) {
  unsigned u = __builtin_bit_cast(unsigned, f);
  u += 0x7FFFu + ((u >> 16) & 1u);
  return (u16)(u >> 16);
}

// ---------------------------------------------------------------------------
// x[b][c][n] fp32 -> xT[b][n][c] bf16   (B=16, C=512, H=32, W=32)
__global__ __launch_bounds__(256) void xpose_cvt(const float* __restrict__ x,
                                                 u16* __restrict__ xT) {
  __shared__ float t[32][33];
  int b = blockIdx.z;
  int n0 = blockIdx.x * 32, c0 = blockIdx.y * 32;
  int tx = threadIdx.x & 31, ty = threadIdx.x >> 5;  // ty 0..7
  const float* xp = x + (size_t)b * 512 * 1024;
#pragma unroll
  for (int i = 0; i < 32; i += 8)
    t[ty + i][tx] = xp[(size_t)(c0 + ty + i) * 1024 + n0 + tx];
  __syncthreads();
  u16* op = xT + (size_t)b * 1024 * 512;
#pragma unroll
  for (int i = 0; i < 32; i += 8)
    op[(size_t)(n0 + ty + i) * 512 + c0 + tx] = to_bf16(t[tx][ty + i]);
}

__global__ __launch_bounds__(256) void cvt_bf16(const float* __restrict__ s,
                                                u16* __restrict__ d, int n) {
  int i = blockIdx.x * 256 + threadIdx.x;
  if (i < n) d[i] = to_bf16(s[i]);
}

// ---------------------------------------------------------------------------
// Generic 128x128-tile bf16 GEMM, K=512, BK=32 (m97 structure; R3-identical,
// LINEAR K/V output layouts).
template <int MODE>
__global__ __launch_bounds__(256) void gemm_bt(
    const u16* __restrict__ Abase, const u16* __restrict__ Bbase,
    long saB, long sbB,
    const float* __restrict__ bias, const float* __restrict__ xres,
    const float* __restrict__ gammap,
    u16* __restrict__ oq, u16* __restrict__ ok, u16* __restrict__ ov,
    float* __restrict__ of) {
  __shared__ __align__(16) u16 lsA[128 * 32];
  __shared__ __align__(16) u16 lsB[128 * 32];
  int b = blockIdx.z;
  const u16* Ag = Abase + (size_t)b * saB;
  const u16* Bg = Bbase + (size_t)b * sbB;
  int m0 = blockIdx.y * 128, n0 = blockIdx.x * 128;
  int tid = threadIdx.x;
  int w = tid >> 6, l = tid & 63;
  int wr = w >> 1, wc = w & 1;
  int lq = l >> 4, lr = l & 15;
  int rowA = w * 32 + (l >> 2);
  int k8 = (l & 3) * 8;
  f32x4 acc[4][4] = {};
  for (int kk = 0; kk < 16; ++kk) {
    int ko = kk * 32;
    __builtin_amdgcn_global_load_lds(
        AS1C(Ag + (size_t)(m0 + rowA) * 512 + ko + k8),
        AS3(&lsA[rowA * 32 + k8]), 16, 0, 0);
    __builtin_amdgcn_global_load_lds(
        AS1C(Ag + (size_t)(m0 + rowA + 16) * 512 + ko + k8),
        AS3(&lsA[(rowA + 16) * 32 + k8]), 16, 0, 0);
    __builtin_amdgcn_global_load_lds(
        AS1C(Bg + (size_t)(n0 + rowA) * 512 + ko + k8),
        AS3(&lsB[rowA * 32 + k8]), 16, 0, 0);
    __builtin_amdgcn_global_load_lds(
        AS1C(Bg + (size_t)(n0 + rowA + 16) * 512 + ko + k8),
        AS3(&lsB[(rowA + 16) * 32 + k8]), 16, 0, 0);
    __syncthreads();
    short8 af[4], bfr[4];
#pragma unroll
    for (int m = 0; m < 4; ++m)
      af[m] = *(const short8*)&lsA[(wr * 64 + m * 16 + lr) * 32 + lq * 8];
#pragma unroll
    for (int j = 0; j < 4; ++j)
      bfr[j] = *(const short8*)&lsB[(wc * 64 + j * 16 + lr) * 32 + lq * 8];
#pragma unroll
    for (int m = 0; m < 4; ++m)
#pragma unroll
      for (int j = 0; j < 4; ++j)
        acc[m][j] = __builtin_amdgcn_mfma_f32_16x16x32_bf16(af[m], bfr[j],
                                                            acc[m][j], 0, 0, 0);
    __syncthreads();
  }
  float g = (MODE == 2) ? gammap[0] : 0.f;
#pragma unroll
  for (int m = 0; m < 4; ++m)
#pragma unroll
    for (int j = 0; j < 4; ++j)
#pragma unroll
      for (int e = 0; e < 4; ++e) {
        int row = m0 + wr * 64 + m * 16 + lq * 4 + e;
        int col = n0 + wc * 64 + j * 16 + lr;
        float v = acc[m][j][e];
        if (MODE == 0) {
          int o = col, n = row;
          v += bias[o];
          int oo = (o < 512) ? o : o - 512;
          int hh = oo >> 6, cc = oo & 63;
          u16* dst = (o < 512) ? oq : ok;
          dst[((size_t)(b * 8 + hh) * 1024 + n) * 64 + cc] = to_bf16(v);
        } else if (MODE == 1) {
          int o = row, n = col;
          v += bias[o];  // bias pre-offset by +1024 on host side
          int hh = o >> 6, cc = o & 63;
          ov[((size_t)(b * 8 + hh) * 64 + cc) * 1024 + n] = to_bf16(v);
        } else {
          int o = row, n = col;
          v += bias[o];
          size_t idx = ((size_t)b * 512 + o) * 1024 + n;
          of[idx] = g * v + xres[idx];
        }
      }
}

// ---------------------------------------------------------------------------
// Flash attention with LDS-shared K/V via REGISTER staging (T14): global->VGPR
// loads for tile t+1 issued at top of iter t (hide under compute), ds_write
// into the back buffer just before the barrier. K/V global layouts LINEAR
// (Q/K [bh][n][64], V [bh][c][n]); XOR swizzle applied at ds_write and
// ds_read with the same (row&7)<<3 convention -> conflict-free b128 reads.
// Constant-max softmax (P = exp2(S*CS - 16*CS)); row-sum via ones-MFMA.
#define CS 0.18033688f   // (1/sqrt(64)) * log2(e)
#define MCC 2.8853901f   // 16 * CS

__global__ __launch_bounds__(256, 3) void attn_fused(const u16* __restrict__ Qb,
                                                     const u16* __restrict__ Kb,
                                                     const u16* __restrict__ Vb,
                                                     u16* __restrict__ attnT) {
  __shared__ __align__(16) u16 KV[2][2][4096];  // [buf][K=0/V=1][64x64 tile]
  __shared__ __align__(16) u16 Plds[4][2048];   // wave-private P, XOR-swizzled
  int L = blockIdx.x;
  // XCD-bijective swizzle: all 8 n-blocks of a bh land on one XCD (L2 reuse)
  int bh = (L & 7) | ((L >> 6) << 3);
  int nb = (L >> 3) & 7;
  int b = bh >> 3, h = bh & 7;
  int tid = threadIdx.x, w = tid >> 6, lane = tid & 63;
  int g = lane >> 4, lr = lane & 15;
  char* Pb = (char*)(&Plds[w][0]);
  const u16* Qh = Qb + (size_t)bh * 65536;
  const u16* Kh = Kb + (size_t)bh * 65536;
  const u16* Vh = Vb + (size_t)bh * 65536;
  int n_base = nb * 128 + w * 32;
  int sz = (lr & 7) << 4;  // P swizzle (bytes)
  int fs = (lr & 7) << 3;  // K/V fragment read swizzle (u16 units)

  // staging geometry: wave w owns rows [16w,16w+16); lane handles one row's
  // 32B x2. dst swizzle uses the STAGED row's (srow&7), matching read side.
  int srow = w * 16 + (lane >> 2);
  int scol = (lane & 3) * 16;
  int sws = (srow & 7) << 3;
  int dst0 = srow * 64 + (scol ^ sws);
  int dst1 = srow * 64 + ((scol + 8) ^ sws);

  const short8 onesf = {0x3F80, 0x3F80, 0x3F80, 0x3F80,
                        0x3F80, 0x3F80, 0x3F80, 0x3F80};  // bf16 1.0 x8

  short8 qf[2][2];
#pragma unroll
  for (int r = 0; r < 2; ++r)
#pragma unroll
    for (int ks = 0; ks < 2; ++ks)
      qf[r][ks] = *(const short8*)&Qh[(size_t)(n_base + r * 16 + lr) * 64 +
                                      ks * 32 + g * 8];

  f32x4 O[2][4] = {};
  f32x4 lacc[2] = {};

  // ---- prologue: stage tile 0 through registers
  {
    short8 kr0 = *(const short8*)&Kh[(size_t)srow * 64 + scol];
    short8 kr1 = *(const short8*)&Kh[(size_t)srow * 64 + scol + 8];
    short8 vr0 = *(const short8*)&Vh[(size_t)srow * 1024 + scol];
    short8 vr1 = *(const short8*)&Vh[(size_t)srow * 1024 + scol + 8];
    *(short8*)&KV[0][0][dst0] = kr0;
    *(short8*)&KV[0][0][dst1] = kr1;
    *(short8*)&KV[0][1][dst0] = vr0;
    *(short8*)&KV[0][1][dst1] = vr1;
  }
  __syncthreads();

  for (int t = 0; t < 16; ++t) {
    const int bf = t & 1;
    // ---- a) issue global loads for tile t+1 (consumed at step f)
    short8 kr0, kr1, vr0, vr1;
    if (t < 15) {
      int off = (t + 1) * 64;
      kr0 = *(const short8*)&Kh[(size_t)(off + srow) * 64 + scol];
      kr1 = *(const short8*)&Kh[(size_t)(off + srow) * 64 + scol + 8];
      vr0 = *(const short8*)&Vh[(size_t)srow * 1024 + off + scol];
      vr1 = *(const short8*)&Vh[(size_t)srow * 1024 + off + scol + 8];
    }
    // ---- b) K fragments from LDS + QK^T (swapped: S row=k, col=q)
    f32x4 S[4][2];
#pragma unroll
    for (int j = 0; j < 4; ++j) {
      short8 k0 =
          *(const short8*)&KV[bf][0][(j * 16 + lr) * 64 + ((g * 8) ^ fs)];
      short8 k1 =
          *(const short8*)&KV[bf][0][(j * 16 + lr) * 64 + ((32 + g * 8) ^ fs)];
#pragma unroll
      for (int r = 0; r < 2; ++r) {
        f32x4 z = {};
        z = __builtin_amdgcn_mfma_f32_16x16x32_bf16(k0, qf[r][0], z, 0, 0, 0);
        z = __builtin_amdgcn_mfma_f32_16x16x32_bf16(k1, qf[r][1], z, 0, 0, 0);
        S[j][r] = z;
      }
    }
    // ---- c) P = exp2(S*CS - 16*CS), pack pairs, 8x ds_write_b64
#pragma unroll
    for (int r = 0; r < 2; ++r) {
      int rowoff = (r * 16 + lr) * 128;
#pragma unroll
      for (int j = 0; j < 4; ++j) {
        float p0 = __builtin_amdgcn_exp2f(__builtin_fmaf(S[j][r][0], CS, -MCC));
        float p1 = __builtin_amdgcn_exp2f(__builtin_fmaf(S[j][r][1], CS, -MCC));
        float p2 = __builtin_amdgcn_exp2f(__builtin_fmaf(S[j][r][2], CS, -MCC));
        float p3 = __builtin_amdgcn_exp2f(__builtin_fmaf(S[j][r][3], CS, -MCC));
        unsigned w0, w1;
        asm("v_cvt_pk_bf16_f32 %0, %1, %2" : "=v"(w0) : "v"(p0), "v"(p1));
        asm("v_cvt_pk_bf16_f32 %0, %1, %2" : "=v"(w1) : "v"(p2), "v"(p3));
        *(uint2v*)(Pb + rowoff + ((j * 32 + g * 8) ^ sz)) = (uint2v){w0, w1};
      }
    }
    // ---- d) P fragments + lsum MFMAs
    short8 pf[2][2];
#pragma unroll
    for (int r = 0; r < 2; ++r) {
      int rowoff = (r * 16 + lr) * 128;
      pf[r][0] = *(const short8*)(Pb + rowoff + ((g * 16) ^ sz));
      pf[r][1] = *(const short8*)(Pb + rowoff + ((64 + g * 16) ^ sz));
      lacc[r] = __builtin_amdgcn_mfma_f32_16x16x32_bf16(pf[r][0], onesf,
                                                        lacc[r], 0, 0, 0);
      lacc[r] = __builtin_amdgcn_mfma_f32_16x16x32_bf16(pf[r][1], onesf,
                                                        lacc[r], 0, 0, 0);
    }
    // ---- e) V fragments from LDS + PV
#pragma unroll
    for (int jc = 0; jc < 4; ++jc) {
      short8 v0 =
          *(const short8*)&KV[bf][1][(jc * 16 + lr) * 64 + ((g * 8) ^ fs)];
      short8 v1 =
          *(const short8*)&KV[bf][1][(jc * 16 + lr) * 64 + ((32 + g * 8) ^ fs)];
#pragma unroll
      for (int r = 0; r < 2; ++r) {
        O[r][jc] = __builtin_amdgcn_mfma_f32_16x16x32_bf16(pf[r][0], v0,
                                                           O[r][jc], 0, 0, 0);
        O[r][jc] = __builtin_amdgcn_mfma_f32_16x16x32_bf16(pf[r][1], v1,
                                                           O[r][jc], 0, 0, 0);
      }
    }
    // ---- f) ds_write staged regs into back buffer, then barrier
    if (t < 15) {
      *(short8*)&KV[bf ^ 1][0][dst0] = kr0;
      *(short8*)&KV[bf ^ 1][0][dst1] = kr1;
      *(short8*)&KV[bf ^ 1][1][dst0] = vr0;
      *(short8*)&KV[bf ^ 1][1][dst1] = vr1;
    }
    __syncthreads();
  }
  // ---- normalize + store attnT[b][n][h*64 + c]; lacc is in O's row layout
#pragma unroll
  for (int r = 0; r < 2; ++r)
#pragma unroll
    for (int e = 0; e < 4; ++e) {
      float rl = 1.0f / lacc[r][e];
      int n = n_base + r * 16 + g * 4 + e;
#pragma unroll
      for (int jc = 0; jc < 4; ++jc)
        attnT[((size_t)b * 1024 + n) * 512 + h * 64 + jc * 16 + lr] =
            to_bf16(O[r][jc][e] * rl);
    }
}

// ---------------------------------------------------------------------------
extern "C" void kernel_launch(void* const* d_in, const int* in_sizes, int n_in,
                              void* d_out, int out_size, void* d_ws,
                              size_t ws_size, hipStream_t stream) {
  const float* x      = (const float*)d_in[0];  // (16,512,32,32)
  const float* qkv_w  = (const float*)d_in[1];  // (1536,512)
  const float* qkv_b  = (const float*)d_in[2];  // (1536,)
  const float* out_w  = (const float*)d_in[3];  // (512,512)
  const float* out_b  = (const float*)d_in[4];  // (512,)
  const float* gamma  = (const float*)d_in[5];  // (1,)
  float* out = (float*)d_out;

  u16* xT  = (u16*)d_ws;          // [16][1024][512]
  u16* Qb  = xT + 8388608;        // [128][1024][64]
  u16* Kbf = Qb + 8388608;        // [128][1024][64]
  u16* Vbf = Kbf + 8388608;       // [128][64][1024]
  u16* aT  = Vbf + 8388608;       // [16][1024][512]
  u16* wq  = aT + 8388608;        // qkv_w bf16 (1536*512)
  u16* wo  = wq + 786432;         // out_w bf16 (512*512)

  // 1) convert / transpose inputs to bf16
  xpose_cvt<<<dim3(32, 16, 16), 256, 0, stream>>>(x, xT);
  cvt_bf16<<<3072, 256, 0, stream>>>(qkv_w, wq, 786432);
  cvt_bf16<<<1024, 256, 0, stream>>>(out_w, wo, 262144);

  // 2) QKV projection. Q,K via transposed orientation (rows=n, cols=o<1024)
  gemm_bt<0><<<dim3(8, 8, 16), 256, 0, stream>>>(
      xT, wq, (long)524288, (long)0, qkv_b, nullptr, nullptr, Qb, Kbf, nullptr,
      nullptr);
  // 3) V via normal orientation (rows=o' in [0,512), cols=n)
  gemm_bt<1><<<dim3(8, 4, 16), 256, 0, stream>>>(
      wq + 524288, xT, (long)0, (long)524288, qkv_b + 1024, nullptr, nullptr,
      nullptr, nullptr, Vbf, nullptr);

  // 4) fused flash attention -> attnT[b][n][512] (reg-staged LDS-shared K/V)
  attn_fused<<<1024, 256, 0, stream>>>(Qb, Kbf, Vbf, aT);

  // 5) output projection + bias + gamma*out + x  -> fp32 d_out
  gemm_bt<2><<<dim3(8, 4, 16), 256, 0, stream>>>(
      wo, aT, (long)0, (long)524288, out_b, x, gamma, nullptr, nullptr, nullptr,
      out);
}